// Round 1
// baseline (43.296 us; speedup 1.0000x reference)
//
#include <hip/hip_runtime.h>

// Problem constants (from reference)
#define N_DOCS 500000
#define N_WORDS 100000
#define EMB 128
#define BATCH 16384
#define CTX 8
#define K 6

// ---------------------------------------------------------------------------
// Kernel A: tiled transpose  Wp [EMB, N_WORDS] -> WpT [N_WORDS, EMB]
// 32x32 tiles, LDS with +1 padding, coalesced reads and writes.
// Grid: (N_WORDS/32 = 3125, EMB/32 = 4), block (32, 8), each thread does 4 rows.
// ---------------------------------------------------------------------------
__global__ __launch_bounds__(256) void transpose_wp(const float* __restrict__ Wp,
                                                    float* __restrict__ WpT) {
    __shared__ float tile[32][33];
    const int ctile = blockIdx.x;  // column tile of Wp (0..3124)
    const int rtile = blockIdx.y;  // row tile of Wp (0..3)
    const int tx = threadIdx.x;    // 0..31
    const int ty = threadIdx.y;    // 0..7

    const int col = ctile * 32 + tx;
#pragma unroll
    for (int j = 0; j < 4; ++j) {
        const int row = rtile * 32 + ty + j * 8;
        tile[ty + j * 8][tx] = Wp[(size_t)row * N_WORDS + col];
    }
    __syncthreads();
    // WpT[c][r] = Wp[r][c];  tile[a][b] = Wp[rtile*32+a][ctile*32+b]
#pragma unroll
    for (int j = 0; j < 4; ++j) {
        const int r = ty + j * 8;  // element within tile
        WpT[(size_t)(ctile * 32 + r) * EMB + rtile * 32 + tx] = tile[tx][r];
    }
}

// ---------------------------------------------------------------------------
// Kernel B: fused  x[b] = D[doc[b]] + sum_c W[ctx[b,c]];  out[b,k] = x[b].WpT[id]
// One wave (64 lanes) per batch element; lane l holds float2 = elems 2l,2l+1.
// Block = 256 threads = 4 waves = 4 batch elements.
// ---------------------------------------------------------------------------
template <bool USE_WPT>
__global__ __launch_bounds__(256) void nce_fused(const float* __restrict__ D,
                                                 const float* __restrict__ W,
                                                 const float* __restrict__ Wpx,  // WpT if USE_WPT else Wp
                                                 const int* __restrict__ ctx_ids,
                                                 const int* __restrict__ doc_ids,
                                                 const int* __restrict__ tn_ids,
                                                 float* __restrict__ out) {
    const int wave = threadIdx.x >> 6;
    const int lane = threadIdx.x & 63;
    const int b = blockIdx.x * 4 + wave;
    if (b >= BATCH) return;

    // x accumulation: coalesced float2 row reads
    const float2* Drow = (const float2*)(D + (size_t)doc_ids[b] * EMB);
    float2 x = Drow[lane];
#pragma unroll
    for (int c = 0; c < CTX; ++c) {
        const int id = ctx_ids[b * CTX + c];
        const float2* Wrow = (const float2*)(W + (size_t)id * EMB);
        const float2 w = Wrow[lane];
        x.x += w.x;
        x.y += w.y;
    }

#pragma unroll
    for (int k = 0; k < K; ++k) {
        const int id = tn_ids[b * K + k];
        float p;
        if (USE_WPT) {
            const float2* row = (const float2*)(Wpx + (size_t)id * EMB);
            const float2 w = row[lane];
            p = x.x * w.x + x.y * w.y;
        } else {
            // strided column gather fallback: Wp[e][id], e = 2*lane, 2*lane+1
            p = x.x * Wpx[(size_t)(2 * lane) * N_WORDS + id] +
                x.y * Wpx[(size_t)(2 * lane + 1) * N_WORDS + id];
        }
        // wave-wide sum (64 lanes)
#pragma unroll
        for (int off = 32; off > 0; off >>= 1) p += __shfl_down(p, off, 64);
        if (lane == 0) out[b * K + k] = p;
    }
}

extern "C" void kernel_launch(void* const* d_in, const int* in_sizes, int n_in,
                              void* d_out, int out_size, void* d_ws, size_t ws_size,
                              hipStream_t stream) {
    const float* D  = (const float*)d_in[0];
    const float* W  = (const float*)d_in[1];
    const float* Wp = (const float*)d_in[2];
    const int* ctx  = (const int*)d_in[3];
    const int* doc  = (const int*)d_in[4];
    const int* tn   = (const int*)d_in[5];
    float* out = (float*)d_out;

    const size_t need = (size_t)N_WORDS * EMB * sizeof(float);
    if (ws_size >= need) {
        float* WpT = (float*)d_ws;
        transpose_wp<<<dim3(N_WORDS / 32, EMB / 32), dim3(32, 8), 0, stream>>>(Wp, WpT);
        nce_fused<true><<<BATCH / 4, 256, 0, stream>>>(D, W, WpT, ctx, doc, tn, out);
    } else {
        nce_fused<false><<<BATCH / 4, 256, 0, stream>>>(D, W, Wp, ctx, doc, tn, out);
    }
}